// Round 12
// baseline (604.031 us; speedup 1.0000x reference)
//
#include <hip/hip_runtime.h>
#include <hip/hip_bf16.h>
#include <math.h>

typedef __bf16 bf16_t;
typedef __attribute__((ext_vector_type(8))) __bf16 bf16x8;
typedef __attribute__((ext_vector_type(2))) __bf16 bf16x2;
typedef __attribute__((ext_vector_type(4))) float f32x4;

// async global->LDS, 16B per lane. dst must be the wave-uniform base (HW adds lane*16).
__device__ __forceinline__ void gld_lds16(const void* g, void* s) {
    __builtin_amdgcn_global_load_lds(
        (__attribute__((address_space(1))) unsigned int*)g,
        (__attribute__((address_space(3))) unsigned int*)s,
        16, 0, 0);
}

// bijective XCD chunk swizzle (m204) + col-fast decode
__device__ __forceinline__ int2 sw_decode(int orig, int nwg, int NT) {
    int q = nwg >> 3, r = nwg & 7, xcd = orig & 7, idx = orig >> 3;
    int wg = (xcd < r ? xcd * (q + 1) : r * (q + 1) + (xcd - r) * q) + idx;
    int bx = wg / NT, by = wg - bx * NT;
    return make_int2(bx, by);
}

// ---------------------------------------------------------------- fused weight prep + buffer zeroing
__device__ __forceinline__ void tconv_tile(const float* __restrict__ in, bf16_t* __restrict__ out,
                                           int R, int C, int rs, int ro, int bx, int by)
{
    __shared__ float tile[32][33];
    int bc = bx * 32, br = by * 32;
    int tx = threadIdx.x & 31, ty = threadIdx.x >> 5;
    #pragma unroll
    for (int i = 0; i < 32; i += 8) {
        int r = br + ty + i, c = bc + tx;
        tile[ty + i][tx] = (r < R && c < C) ? in[(long)r * C + c] : 0.f;
    }
    __syncthreads();
    #pragma unroll
    for (int i = 0; i < 32; i += 8) {
        int c = bc + ty + i, r = br + tx;
        if (c < C && r < R) out[((long)c * rs + ro) * R + r] = (bf16_t)tile[tx][ty + i];
    }
}

__global__ __launch_bounds__(256) void k_prep(const float* __restrict__ fc_w, bf16_t* __restrict__ fcT,
                                              const float* __restrict__ conv_w1, bf16_t* __restrict__ w1T,
                                              const float* __restrict__ conv_w2, bf16_t* __restrict__ w2T,
                                              const float* __restrict__ phi_w, bf16_t* __restrict__ phiT,
                                              const float* __restrict__ aw, const float* __restrict__ bw,
                                              bf16_t* __restrict__ Bcat,
                                              const float* __restrict__ abias, const float* __restrict__ bbias,
                                              float* __restrict__ bias_cat,
                                              int* __restrict__ deg, float* __restrict__ sN,
                                              float* __restrict__ hp, int Nn)
{
    int b = blockIdx.x;
    if (b < 128) {
        tconv_tile(fc_w, fcT, 1024, 128, 1, 0, b & 3, b >> 2);
    } else if (b < 224) {
        int i = (b - 128) >> 5, bb = (b - 128) & 31;
        tconv_tile(conv_w1 + (size_t)i * 128 * 256, w1T + (size_t)i * 256 * 128, 128, 256, 1, 0, bb & 7, bb >> 3);
    } else if (b < 320) {
        int i = (b - 224) >> 5, bb = (b - 224) & 31;
        tconv_tile(conv_w2 + (size_t)i * 256 * 128, w2T + (size_t)i * 128 * 256, 256, 128, 1, 0, bb & 3, bb >> 2);
    } else if (b < 576) {
        int bb = b - 320;
        tconv_tile(phi_w, phiT, 512, 512, 1, 0, bb & 15, bb >> 4);
    } else if (b < 832) {
        int bb = b - 576;
        tconv_tile(aw, Bcat, 512, 512, 2, 0, bb & 15, bb >> 4);
    } else if (b < 1088) {
        int bb = b - 832;
        tconv_tile(bw, Bcat, 512, 512, 2, 1, bb & 15, bb >> 4);
    } else if (b < 1090) {
        int i = (b - 1088) * 256 + threadIdx.x;
        if (i < 512) { bias_cat[2 * i] = abias[i]; bias_cat[2 * i + 1] = bbias[i]; }
    } else if (b < 1286) {
        int i = (b - 1090) * 256 + threadIdx.x;
        if (i < Nn) deg[i] = 0;
    } else if (b < 1482) {
        int i = (b - 1286) * 256 + threadIdx.x;
        if (i < Nn) sN[i] = 0.f;
    } else {
        // 256-thread block: zero BOTH halves of hp[512] (R11 bug: only hp[0..255] was reset,
        // so pool atomics accumulated across graph replays -> tripwire)
        hp[threadIdx.x] = 0.f;
        hp[threadIdx.x + 256] = 0.f;
    }
}

// ---------------------------------------------------------------- CSR build
__global__ __launch_bounds__(256) void k_deg(const int* __restrict__ dst, int* __restrict__ deg, int E)
{
    int e = blockIdx.x * 256 + threadIdx.x;
    if (e < E) atomicAdd(&deg[dst[e]], 1);
}

__global__ __launch_bounds__(1024) void k_scan_a(const int* __restrict__ deg, int* __restrict__ loc,
                                                 int* __restrict__ bsum, int n)
{
    __shared__ int wsum[16];
    int t = threadIdx.x, lane = t & 63, wid = t >> 6;
    int idx = blockIdx.x * 1024 + t;
    int v = (idx < n) ? deg[idx] : 0;
    int x = v;
    #pragma unroll
    for (int d = 1; d < 64; d <<= 1) { int o = __shfl_up(x, d); if (lane >= d) x += o; }
    if (lane == 63) wsum[wid] = x;
    __syncthreads();
    if (wid == 0 && lane < 16) {
        int y = wsum[lane];
        #pragma unroll
        for (int d = 1; d < 16; d <<= 1) { int o = __shfl_up(y, d); if (lane >= d) y += o; }
        wsum[lane] = y;
    }
    __syncthreads();
    int wbase = (wid == 0) ? 0 : wsum[wid - 1];
    if (idx < n) loc[idx] = wbase + x - v;
    if (t == 1023) bsum[blockIdx.x] = wsum[15];
}

__global__ __launch_bounds__(64) void k_scan_b(const int* __restrict__ bsum, int nb,
                                               int* __restrict__ boff, int* __restrict__ off_n)
{
    int lane = threadIdx.x;
    int base = 0;
    for (int c = 0; c < nb; c += 64) {
        int i = c + lane;
        int v = (i < nb) ? bsum[i] : 0;
        int x = v;
        #pragma unroll
        for (int d = 1; d < 64; d <<= 1) { int o = __shfl_up(x, d); if (lane >= d) x += o; }
        if (i < nb) boff[i] = base + x - v;
        base += __shfl(x, 63);
    }
    if (lane == 0) *off_n = base;
}

__global__ __launch_bounds__(1024) void k_scan_c(const int* __restrict__ loc, const int* __restrict__ boff,
                                                 int* __restrict__ off, int* __restrict__ cursor, int n)
{
    int idx = blockIdx.x * 1024 + threadIdx.x;
    if (idx < n) { int v = loc[idx] + boff[blockIdx.x]; off[idx] = v; cursor[idx] = v; }
}

__global__ __launch_bounds__(256) void k_fill(const int* __restrict__ src, const int* __restrict__ dst,
                                              int* __restrict__ cursor, int* __restrict__ csr, int E)
{
    int e = blockIdx.x * 256 + threadIdx.x;
    if (e < E) {
        int d = dst[e];
        int pos = atomicAdd(&cursor[d], 1);
        csr[pos] = src[e];
    }
}

// ---------------------------------------------------------------- GENConv aggregation, 8-deep prefetch
__global__ __launch_bounds__(256) void k_agg(const bf16_t* __restrict__ X,
                                             const int* __restrict__ off, const int* __restrict__ csr,
                                             bf16_t* __restrict__ haux,
                                             const float* __restrict__ tptr, int ti, int Nn)
{
    int w = (blockIdx.x * 256 + threadIdx.x) >> 6;
    if (w >= Nn) return;
    int lane = threadIdx.x & 63;
    float t = tptr[ti];
    int e0 = off[w], e1 = off[w + 1];
    float m0 = -__builtin_inff(), m1 = -__builtin_inff();
    float s0 = 0.f, s1 = 0.f, g0 = 0.f, g1 = 0.f;

    auto proc = [&](bf16x2 xv) {
        float msg0 = fmaxf((float)xv[0], 0.f) + 1e-7f;
        float msg1 = fmaxf((float)xv[1], 0.f) + 1e-7f;
        float v0 = msg0 * t, v1 = msg1 * t;
        if (v0 > m0) { float sc = __expf(m0 - v0); s0 *= sc; g0 *= sc; m0 = v0; }
        float p0 = __expf(v0 - m0); s0 += p0; g0 += msg0 * p0;
        if (v1 > m1) { float sc = __expf(m1 - v1); s1 *= sc; g1 *= sc; m1 = v1; }
        float p1 = __expf(v1 - m1); s1 += p1; g1 += msg1 * p1;
    };

    int e = e0;
    for (; e + 8 <= e1; e += 8) {
        int i0 = csr[e],     i1 = csr[e + 1], i2 = csr[e + 2], i3 = csr[e + 3];
        int i4 = csr[e + 4], i5 = csr[e + 5], i6 = csr[e + 6], i7 = csr[e + 7];
        bf16x2 v0 = *(const bf16x2*)(X + (long)i0 * 128 + lane * 2);
        bf16x2 v1 = *(const bf16x2*)(X + (long)i1 * 128 + lane * 2);
        bf16x2 v2 = *(const bf16x2*)(X + (long)i2 * 128 + lane * 2);
        bf16x2 v3 = *(const bf16x2*)(X + (long)i3 * 128 + lane * 2);
        bf16x2 v4 = *(const bf16x2*)(X + (long)i4 * 128 + lane * 2);
        bf16x2 v5 = *(const bf16x2*)(X + (long)i5 * 128 + lane * 2);
        bf16x2 v6 = *(const bf16x2*)(X + (long)i6 * 128 + lane * 2);
        bf16x2 v7 = *(const bf16x2*)(X + (long)i7 * 128 + lane * 2);
        proc(v0); proc(v1); proc(v2); proc(v3); proc(v4); proc(v5); proc(v6); proc(v7);
    }
    for (; e + 4 <= e1; e += 4) {
        int i0 = csr[e], i1 = csr[e + 1], i2 = csr[e + 2], i3 = csr[e + 3];
        bf16x2 v0 = *(const bf16x2*)(X + (long)i0 * 128 + lane * 2);
        bf16x2 v1 = *(const bf16x2*)(X + (long)i1 * 128 + lane * 2);
        bf16x2 v2 = *(const bf16x2*)(X + (long)i2 * 128 + lane * 2);
        bf16x2 v3 = *(const bf16x2*)(X + (long)i3 * 128 + lane * 2);
        proc(v0); proc(v1); proc(v2); proc(v3);
    }
    for (; e < e1; e++) {
        int s = csr[e];
        bf16x2 xv = *(const bf16x2*)(X + (long)s * 128 + lane * 2);
        proc(xv);
    }
    float a0 = g0 / (s0 + 1e-16f);
    float a1 = g1 / (s1 + 1e-16f);
    bf16x2 xr = *(const bf16x2*)(X + (long)w * 128 + lane * 2);
    bf16_t* outp = haux + (long)w * 128 + lane * 2;
    outp[0] = (bf16_t)((float)xr[0] + a0);
    outp[1] = (bf16_t)((float)xr[1] + a1);
}

// ---------------------------------------------------------------- 1-phase GEMM (proven structure), BN=128.
// BM=512: 1024 thr, 16 waves (8Mx2N), 80 KB -> 2 blocks/CU = 32 waves (100% wave occ).
// EPI 3 = bf16 relu store; EPI 5 = interleaved attention epilogue (cols 2j/2j+1 = a/b).
template<int BM, int EPI>
__global__ __launch_bounds__((BM == 512) ? 1024 : 512, 4)
void k_gemm1(const bf16_t* __restrict__ A, int lda,
             const bf16_t* __restrict__ BT,
             const float* __restrict__ bias,
             bf16_t* __restrict__ Cout, int ldc,
             int M, int K, int NT,
             const float* __restrict__ cw,
             float* __restrict__ sout)
{
    constexpr int THREADS = (BM == 512) ? 1024 : 512;
    constexpr int ACH = BM * 8 / THREADS;
    constexpr int BCH = 128 * 8 / THREADS;
    __shared__ __align__(16) bf16_t lA[BM * 64];
    __shared__ __align__(16) bf16_t lB[128 * 64];
    int2 bxy = sw_decode(blockIdx.x, gridDim.x, NT);
    const int m0 = bxy.x * BM, n0 = bxy.y * 128;
    const int tid = threadIdx.x, lane = tid & 63, wid = tid >> 6;
    const int rbase = (wid >> 1) * 64, cbase = (wid & 1) * 64;
    const int lrow = lane & 15, kg = lane >> 4;
    const int uw = tid & ~63;

    f32x4 acc[4][4];
    #pragma unroll
    for (int m = 0; m < 4; m++)
        #pragma unroll
        for (int n = 0; n < 4; n++)
            #pragma unroll
            for (int r = 0; r < 4; r++) acc[m][n][r] = 0.f;

    auto stage = [&](int k0) {
        #pragma unroll
        for (int c = 0; c < ACH; c++) {
            int s = c * THREADS + tid, row = s >> 3, k8s = (s & 7) ^ (row & 7);
            int gr = m0 + row; gr = gr < M ? gr : M - 1;   // clamp: garbage only in rows >= M
            gld_lds16(A + (long)gr * lda + k0 + k8s * 8, lA + (c * THREADS + uw) * 8);
        }
        #pragma unroll
        for (int c = 0; c < BCH; c++) {
            int s = c * THREADS + tid, row = s >> 3, k8s = (s & 7) ^ (row & 7);
            gld_lds16(BT + (long)(n0 + row) * K + k0 + k8s * 8, lB + (c * THREADS + uw) * 8);
        }
    };
    auto compute = [&]() {
        #pragma unroll
        for (int ks = 0; ks < 2; ks++) {
            int k8 = ks * 4 + kg;
            bf16x8 af[4], bfr[4];
            #pragma unroll
            for (int m = 0; m < 4; m++) {
                int r = rbase + m * 16 + lrow;
                af[m] = *(const bf16x8*)&lA[(r * 8 + (k8 ^ (r & 7))) * 8];
            }
            #pragma unroll
            for (int n = 0; n < 4; n++) {
                int r = cbase + n * 16 + lrow;
                bfr[n] = *(const bf16x8*)&lB[(r * 8 + (k8 ^ (r & 7))) * 8];
            }
            #pragma unroll
            for (int m = 0; m < 4; m++)
                #pragma unroll
                for (int n = 0; n < 4; n++)
                    acc[m][n] = __builtin_amdgcn_mfma_f32_16x16x32_bf16(af[m], bfr[n], acc[m][n], 0, 0, 0);
        }
    };

    for (int k0 = 0; k0 < K; k0 += 64) {
        stage(k0);
        __syncthreads();
        compute();
        __syncthreads();
    }

    if constexpr (EPI == 5) {
        #pragma unroll
        for (int m = 0; m < 4; m++) {
            #pragma unroll
            for (int r = 0; r < 4; r++) {
                int row = m0 + rbase + m * 16 + kg * 4 + r;   // C/D: col=lane&15, row=(lane>>4)*4+reg
                float val = 0.f;
                #pragma unroll
                for (int n = 0; n < 4; n++) {
                    int col = n0 + cbase + n * 16 + lrow;
                    float xv = acc[m][n][r] + bias[col];
                    int odd = col & 1;
                    float z = odd ? xv : 2.f * xv;
                    float sg = 1.f / (1.f + __expf(-z));
                    float f = odd ? sg : (2.f * sg - 1.f);    // even col: tanh via sigmoid
                    float partner = __shfl_xor(f, 1);
                    float prod = f * partner;
                    val += odd ? 0.f : prod * cw[col >> 1];
                }
                #pragma unroll
                for (int o = 1; o < 16; o <<= 1) val += __shfl_xor(val, o);
                if (lrow == 0 && row < M) atomicAdd(&sout[row], val);
            }
        }
    } else {
        #pragma unroll
        for (int m = 0; m < 4; m++) {
            #pragma unroll
            for (int r = 0; r < 4; r++) {
                int row = m0 + rbase + m * 16 + kg * 4 + r;
                if (row >= M) continue;
                #pragma unroll
                for (int n = 0; n < 4; n++) {
                    int col = n0 + cbase + n * 16 + lrow;
                    float xv = fmaxf(acc[m][n][r] + bias[col], 0.f);
                    Cout[(long)row * ldc + col] = (bf16_t)xv;
                }
            }
        }
    }
}

// ---------------------------------------------------------------- fc GEMM: BM=128, BN=128, f32 A, 1-phase.
__global__ __launch_bounds__(256) void k_gemm_fcP(const float* __restrict__ Aptr, int lda,
                                                  const bf16_t* __restrict__ BT,
                                                  const float* __restrict__ bias,
                                                  bf16_t* __restrict__ Cout, int ldc,
                                                  bf16_t* __restrict__ Cout2,
                                                  int M, int K)
{
    __shared__ __align__(16) bf16_t lA[128 * 64];
    __shared__ __align__(16) bf16_t lB[128 * 64];
    const int m0 = blockIdx.x * 128;
    const int tid = threadIdx.x, lane = tid & 63, wid = tid >> 6;
    const int rbase = (wid >> 1) * 64, cbase = (wid & 1) * 64;
    const int lrow = lane & 15, kg = lane >> 4;
    const int uw = tid & ~63;

    f32x4 acc[4][4];
    #pragma unroll
    for (int m = 0; m < 4; m++)
        #pragma unroll
        for (int n = 0; n < 4; n++)
            #pragma unroll
            for (int r = 0; r < 4; r++) acc[m][n][r] = 0.f;

    f32x4 fa[8];

    for (int k0 = 0; k0 < K; k0 += 64) {
        #pragma unroll
        for (int c = 0; c < 4; c++) {
            int s = c * 256 + tid, row = s >> 3, k8 = s & 7;
            int gr = m0 + row; gr = gr < M ? gr : M - 1;
            const float* sp = Aptr + (long)gr * lda + k0 + k8 * 8;
            fa[2 * c] = *(const f32x4*)sp;
            fa[2 * c + 1] = *(const f32x4*)(sp + 4);
        }
        #pragma unroll
        for (int c = 0; c < 4; c++) {
            int s = c * 256 + tid, row = s >> 3, k8s = (s & 7) ^ (row & 7);
            gld_lds16(BT + (long)row * K + k0 + k8s * 8, lB + (c * 256 + uw) * 8);
        }
        #pragma unroll
        for (int c = 0; c < 4; c++) {
            int s = c * 256 + tid, row = s >> 3, k8 = s & 7;
            bf16x8 v;
            #pragma unroll
            for (int j = 0; j < 4; j++) { v[j] = (bf16_t)fa[2 * c][j]; v[4 + j] = (bf16_t)fa[2 * c + 1][j]; }
            *(bf16x8*)&lA[(row * 8 + (k8 ^ (row & 7))) * 8] = v;
        }
        __syncthreads();
        #pragma unroll
        for (int ks = 0; ks < 2; ks++) {
            int k8 = ks * 4 + kg;
            bf16x8 af[4], bfr[4];
            #pragma unroll
            for (int m = 0; m < 4; m++) {
                int r = rbase + m * 16 + lrow;
                af[m] = *(const bf16x8*)&lA[(r * 8 + (k8 ^ (r & 7))) * 8];
            }
            #pragma unroll
            for (int n = 0; n < 4; n++) {
                int r = cbase + n * 16 + lrow;
                bfr[n] = *(const bf16x8*)&lB[(r * 8 + (k8 ^ (r & 7))) * 8];
            }
            #pragma unroll
            for (int m = 0; m < 4; m++)
                #pragma unroll
                for (int n = 0; n < 4; n++)
                    acc[m][n] = __builtin_amdgcn_mfma_f32_16x16x32_bf16(af[m], bfr[n], acc[m][n], 0, 0, 0);
        }
        __syncthreads();
    }

    #pragma unroll
    for (int m = 0; m < 4; m++) {
        #pragma unroll
        for (int r = 0; r < 4; r++) {
            int row = m0 + rbase + m * 16 + kg * 4 + r;
            if (row >= M) continue;
            #pragma unroll
            for (int n = 0; n < 4; n++) {
                int col = cbase + n * 16 + lrow;
                float xv = fmaxf(acc[m][n][r] + bias[col], 0.f);
                Cout[(long)row * ldc + col] = (bf16_t)xv;
                Cout2[(long)row * 128 + col] = (bf16_t)xv;
            }
        }
    }
}

// ---------------------------------------------------------------- FUSED conv MLP v2 (unchanged)
template<int MODE>  // 0: y=conv; 1: y = xs_in + relu(LN128(conv))
__global__ __launch_bounds__(512) void k_convf(const bf16_t* __restrict__ A,
                                               const bf16_t* __restrict__ B1T,   // [256][128]
                                               const float* __restrict__ b1,
                                               const float* __restrict__ lnw, const float* __restrict__ lnb,
                                               const bf16_t* __restrict__ B2T,   // [128][256]
                                               const float* __restrict__ b2,
                                               const float* __restrict__ nw, const float* __restrict__ nb,
                                               const float* __restrict__ xs_in,
                                               bf16_t* __restrict__ xcat_out,
                                               float* __restrict__ xs_out, bf16_t* __restrict__ xl_out,
                                               int M)
{
    __shared__ __align__(16) bf16_t lA[128 * 128];
    __shared__ __align__(16) bf16_t lB1[256 * 128];
    __shared__ __align__(16) bf16_t lB2a[128 * 128];
    bf16_t* h1 = lB1;
    bf16_t* lB2b = lA;

    const int m0 = blockIdx.x * 128;
    const int tid = threadIdx.x, lane = tid & 63, w = tid >> 6;
    const int lrow = lane & 15, kg = lane >> 4;
    const int uw = tid & ~63;

    #pragma unroll
    for (int c = 0; c < 4; c++) {
        int s = c * 512 + tid, row = s >> 4, sl = s & 15;
        int k8 = (sl & 8) | ((sl & 7) ^ (row & 7));
        int gr = m0 + row; gr = gr < M ? gr : M - 1;
        gld_lds16(A + (long)gr * 128 + k8 * 8, lA + (c * 512 + uw) * 8);
    }
    #pragma unroll
    for (int c = 0; c < 8; c++) {
        int s = c * 512 + tid, row = s >> 4, sl = s & 15;
        int k8 = (sl & 8) | ((sl & 7) ^ (row & 7));
        gld_lds16(B1T + (long)row * 128 + k8 * 8, lB1 + (c * 512 + uw) * 8);
    }
    #pragma unroll
    for (int c = 0; c < 4; c++) {
        int s = c * 512 + tid, row = s >> 4, sl = s & 15;
        int k8 = (sl & 8) | ((sl & 7) ^ (row & 7));
        gld_lds16(B2T + (long)row * 256 + k8 * 8, lB2a + (c * 512 + uw) * 8);
    }
    asm volatile("s_waitcnt vmcnt(4)" ::: "memory");
    __builtin_amdgcn_s_barrier();

    f32x4 acc1[16];
    #pragma unroll
    for (int n = 0; n < 16; n++)
        #pragma unroll
        for (int r = 0; r < 4; r++) acc1[n][r] = 0.f;
    #pragma unroll
    for (int ks = 0; ks < 4; ks++) {
        int k8 = ks * 4 + kg;
        int ra = w * 16 + lrow;
        bf16x8 af = *(const bf16x8*)&lA[(ra * 16 + ((k8 & 8) | ((k8 & 7) ^ (ra & 7)))) * 8];
        #pragma unroll
        for (int n = 0; n < 16; n++) {
            int rb = n * 16 + lrow;
            bf16x8 bf = *(const bf16x8*)&lB1[(rb * 16 + ((k8 & 8) | ((k8 & 7) ^ (rb & 7)))) * 8];
            acc1[n] = __builtin_amdgcn_mfma_f32_16x16x32_bf16(af, bf, acc1[n], 0, 0, 0);
        }
    }

    float hv[4][16];
    #pragma unroll
    for (int r = 0; r < 4; r++) {
        float s1 = 0.f, s2 = 0.f;
        #pragma unroll
        for (int n = 0; n < 16; n++) {
            int col = n * 16 + lrow;
            float xv = acc1[n][r] + b1[col];
            hv[r][n] = xv;
            s1 += xv; s2 += xv * xv;
        }
        #pragma unroll
        for (int o = 1; o < 16; o <<= 1) { s1 += __shfl_xor(s1, o); s2 += __shfl_xor(s2, o); }
        float mu = s1 * (1.f / 256.f);
        float var = s2 * (1.f / 256.f) - mu * mu;
        float rstd = rsqrtf(var + 1e-5f);
        #pragma unroll
        for (int n = 0; n < 16; n++) {
            int col = n * 16 + lrow;
            hv[r][n] = fmaxf((hv[r][n] - mu) * rstd * lnw[col] + lnb[col], 0.f);
        }
    }

    __builtin_amdgcn_s_barrier();

    #pragma unroll
    for (int r = 0; r < 4; r++) {
        int row = w * 16 + kg * 4 + r;
        #pragma unroll
        for (int n = 0; n < 16; n++) {
            int col = n * 16 + lrow;
            int chunk = col >> 3;
            int cs = (chunk & 24) | ((chunk & 7) ^ (row & 7));
            h1[row * 256 + cs * 8 + (col & 7)] = (bf16_t)hv[r][n];
        }
    }
    #pragma unroll
    for (int c = 0; c < 4; c++) {
        int s = c * 512 + tid, row = s >> 4, sl = s & 15;
        int k8l = (sl & 8) | ((sl & 7) ^ (row & 7));
        gld_lds16(B2T + (long)row * 256 + (16 + k8l) * 8, lB2b + (c * 512 + uw) * 8);
    }

    f32x4 acc2[8];
    #pragma unroll
    for (int n = 0; n < 8; n++)
        #pragma unroll
        for (int r = 0; r < 4; r++) acc2[n][r] = 0.f;
    #pragma unroll
    for (int ks = 0; ks < 4; ks++) {
        int k8 = ks * 4 + kg;
        int ra = w * 16 + lrow;
        bf16x8 af = *(const bf16x8*)&h1[(ra * 32 + ((k8 & 24) | ((k8 & 7) ^ (ra & 7)))) * 8];
        #pragma unroll
        for (int n = 0; n < 8; n++) {
            int rb = n * 16 + lrow;
            bf16x8 bf = *(const bf16x8*)&lB2a[(rb * 16 + ((k8 & 8) | ((k8 & 7) ^ (rb & 7)))) * 8];
            acc2[n] = __builtin_amdgcn_mfma_f32_16x16x32_bf16(af, bf, acc2[n], 0, 0, 0);
        }
    }
    asm volatile("s_waitcnt vmcnt(0)" ::: "memory");
    __builtin_amdgcn_s_barrier();

    #pragma unroll
    for (int ks = 0; ks < 4; ks++) {
        int k8 = 16 + ks * 4 + kg;
        int k8l = k8 - 16;
        int ra = w * 16 + lrow;
        bf16x8 af = *(const bf16x8*)&h1[(ra * 32 + ((k8 & 24) | ((k8 & 7) ^ (ra & 7)))) * 8];
        #pragma unroll
        for (int n = 0; n < 8; n++) {
            int rb = n * 16 + lrow;
            bf16x8 bf = *(const bf16x8*)&lB2b[(rb * 16 + ((k8l & 8) | ((k8l & 7) ^ (rb & 7)))) * 8];
            acc2[n] = __builtin_amdgcn_mfma_f32_16x16x32_bf16(af, bf, acc2[n], 0, 0, 0);
        }
    }

    #pragma unroll
    for (int r = 0; r < 4; r++) {
        int row = m0 + w * 16 + kg * 4 + r;
        float xv[8];
        #pragma unroll
        for (int n = 0; n < 8; n++) xv[n] = acc2[n][r] + b2[n * 16 + lrow];
        if constexpr (MODE == 1) {
            float s1 = 0.f, s2 = 0.f;
            #pragma unroll
            for (int n = 0; n < 8; n++) { s1 += xv[n]; s2 += xv[n] * xv[n]; }
            #pragma unroll
            for (int o = 1; o < 16; o <<= 1) { s1 += __shfl_xor(s1, o); s2 += __shfl_xor(s2, o); }
            float mu = s1 * (1.f / 128.f);
            float var = s2 * (1.f / 128.f) - mu * mu;
            float rstd = rsqrtf(var + 1e-5f);
            if (row < M) {
                #pragma unroll
                for (int n = 0; n < 8; n++) {
                    int col = n * 16 + lrow;
                    xv[n] = xs_in[(long)row * 128 + col] + fmaxf((xv[n] - mu) * rstd * nw[col] + nb[col], 0.f);
                }
            }
        }
        if (row < M) {
            #pragma unroll
            for (int n = 0; n < 8; n++) {
                int col = n * 16 + lrow;
                xcat_out[(long)row * 512 + col] = (bf16_t)xv[n];
                if (xs_out) xs_out[(long)row * 128 + col] = xv[n];
                if (xl_out) xl_out[(long)row * 128 + col] = (bf16_t)xv[n];
            }
        }
    }
}

// ---------------------------------------------------------------- parallel softmax stats: partials then combine
__global__ __launch_bounds__(256) void k_sred_a(const float* __restrict__ sN, int Nn,
                                                float* __restrict__ pmax, float* __restrict__ psum)
{
    __shared__ float red[4];
    int t = threadIdx.x, lane = t & 63, wid = t >> 6;
    int stride = gridDim.x * 256;
    float m = -__builtin_inff();
    for (int i = blockIdx.x * 256 + t; i < Nn; i += stride) m = fmaxf(m, sN[i]);
    #pragma unroll
    for (int o = 32; o >= 1; o >>= 1) m = fmaxf(m, __shfl_xor(m, o));
    if (lane == 0) red[wid] = m;
    __syncthreads();
    float bm = fmaxf(fmaxf(red[0], red[1]), fmaxf(red[2], red[3]));
    float s = 0.f;
    for (int i = blockIdx.x * 256 + t; i < Nn; i += stride) s += __expf(sN[i] - bm);
    #pragma unroll
    for (int o = 32; o >= 1; o >>= 1) s += __shfl_xor(s, o);
    __syncthreads();
    if (lane == 0) red[wid] = s;
    __syncthreads();
    if (t == 0) {
        pmax[blockIdx.x] = bm;
        psum[blockIdx.x] = red[0] + red[1] + red[2] + red[3];
    }
}

__global__ __launch_bounds__(64) void k_sred_b(const float* __restrict__ pmax, const float* __restrict__ psum,
                                               int nb, float* __restrict__ red)
{
    int lane = threadIdx.x;
    float m = (lane < nb) ? pmax[lane] : -__builtin_inff();
    #pragma unroll
    for (int o = 32; o >= 1; o >>= 1) m = fmaxf(m, __shfl_xor(m, o));
    float s = (lane < nb) ? psum[lane] * __expf(pmax[lane] - m) : 0.f;
    #pragma unroll
    for (int o = 32; o >= 1; o >>= 1) s += __shfl_xor(s, o);
    if (lane == 0) { red[0] = m; red[1] = s; }
}

// ---------------------------------------------------------------- hp[512] = sum_n softmax(s)[n] * h[n,:]
__global__ __launch_bounds__(256) void k_pool(const bf16_t* __restrict__ h, const float* __restrict__ sN,
                                              const float* __restrict__ red, float* __restrict__ hp, int Nn)
{
    __shared__ float part[4][512];
    int t = threadIdx.x, lane = t & 63, w = t >> 6;
    float m = red[0], inv = 1.f / red[1];
    float acc[8];
    #pragma unroll
    for (int j = 0; j < 8; j++) acc[j] = 0.f;
    for (int n = blockIdx.x * 4 + w; n < Nn; n += gridDim.x * 4) {
        float wgt = __expf(sN[n] - m) * inv;
        bf16x8 v = *(const bf16x8*)(h + (long)n * 512 + lane * 8);
        #pragma unroll
        for (int j = 0; j < 8; j++) acc[j] += wgt * (float)v[j];
    }
    #pragma unroll
    for (int j = 0; j < 8; j++) part[w][lane * 8 + j] = acc[j];
    __syncthreads();
    #pragma unroll
    for (int c = 0; c < 2; c++) {
        int col = c * 256 + t;
        float s = part[0][col] + part[1][col] + part[2][col] + part[3][col];
        atomicAdd(&hp[col], s);
    }
}

// ---------------------------------------------------------------- tail split: h2 = relu(hp@rho+rb) (8 blocks)
__global__ __launch_bounds__(256) void k_tail_a(const float* __restrict__ hp,
                                                const float* __restrict__ rho_w, const float* __restrict__ rho_b,
                                                float* __restrict__ h2g)
{
    __shared__ float hs[512];
    __shared__ float part[256];
    int t = threadIdx.x;
    hs[t] = hp[t]; hs[t + 256] = hp[t + 256];
    __syncthreads();
    int col = blockIdx.x * 64 + (t & 63);
    int ks = t >> 6;
    float acc = 0.f;
    for (int k = ks * 128; k < ks * 128 + 128; k++) acc += hs[k] * rho_w[(long)k * 512 + col];
    part[t] = acc;
    __syncthreads();
    if (ks == 0) {
        float v = part[t] + part[t + 64] + part[t + 128] + part[t + 192] + rho_b[col];
        h2g[col] = fmaxf(v, 0.f);
    }
}

__global__ __launch_bounds__(256) void k_tail_b(const float* __restrict__ h2g,
                                                const float* __restrict__ cls_w, const float* __restrict__ cls_b,
                                                float* __restrict__ out)
{
    __shared__ float wred[4][4];
    int t = threadIdx.x, lane = t & 63, wid = t >> 6;
    float a0 = 0.f, a1 = 0.f, a2 = 0.f, a3 = 0.f;
    for (int d = t; d < 512; d += 256) {
        float h = h2g[d];
        a0 += h * cls_w[d * 4 + 0];
        a1 += h * cls_w[d * 4 + 1];
        a2 += h * cls_w[d * 4 + 2];
        a3 += h * cls_w[d * 4 + 3];
    }
    #pragma unroll
    for (int o = 32; o >= 1; o >>= 1) {
        a0 += __shfl_xor(a0, o); a1 += __shfl_xor(a1, o);
        a2 += __shfl_xor(a2, o); a3 += __shfl_xor(a3, o);
    }
    if (lane == 0) { wred[wid][0] = a0; wred[wid][1] = a1; wred[wid][2] = a2; wred[wid][3] = a3; }
    __syncthreads();
    if (t < 4)
        out[t] = cls_b[t] + wred[0][t] + wred[1][t] + wred[2][t] + wred[3][t];
}

// ================================================================ host
extern "C" void kernel_launch(void* const* d_in, const int* in_sizes, int n_in,
                              void* d_out, int out_size, void* d_ws, size_t ws_size,
                              hipStream_t stream)
{
    const float* x       = (const float*)d_in[0];
    const int*   eidx    = (const int*)  d_in[1];
    const float* fc_w    = (const float*)d_in[2];
    const float* fc_b    = (const float*)d_in[3];
    const float* conv_w1 = (const float*)d_in[4];
    const float* conv_b1 = (const float*)d_in[5];
    const float* conv_lnw= (const float*)d_in[6];
    const float* conv_lnb= (const float*)d_in[7];
    const float* conv_w2 = (const float*)d_in[8];
    const float* conv_b2 = (const float*)d_in[9];
    const float* conv_t  = (const float*)d_in[10];
    const float* norm_w  = (const float*)d_in[11];
    const float* norm_b  = (const float*)d_in[12];
    const float* phi_w   = (const float*)d_in[13];
    const float* phi_b   = (const float*)d_in[14];
    const float* aw      = (const float*)d_in[15];
    const float* ab      = (const float*)d_in[16];
    const float* bw      = (const float*)d_in[17];
    const float* bb      = (const float*)d_in[18];
    const float* cwp     = (const float*)d_in[19];
    // d_in[20] = attn_c_b: constant pre-softmax shift, cancels
    const float* rho_w   = (const float*)d_in[21];
    const float* rho_b   = (const float*)d_in[22];
    const float* cls_w   = (const float*)d_in[23];
    const float* cls_b   = (const float*)d_in[24];

    const int Nn = in_sizes[0] / 1024;
    const int E  = in_sizes[1] / 2;

    char* p = (char*)d_ws;
    auto carve = [&](size_t bytes) { char* r = p; p += (bytes + 255) & ~(size_t)255; return r; };

    bf16_t* x_cat_b = (bf16_t*)carve((size_t)Nn * 512 * 2);
    bf16_t* haux    = (bf16_t*)carve((size_t)Nn * 128 * 2);
    float*  xs1     = (float*)carve((size_t)Nn * 128 * 4);
    float*  xs2     = (float*)carve((size_t)Nn * 128 * 4);
    bf16_t* xl0     = (bf16_t*)carve((size_t)Nn * 128 * 2);
    bf16_t* xl1     = (bf16_t*)carve((size_t)Nn * 128 * 2);
    bf16_t* xl2     = (bf16_t*)carve((size_t)Nn * 128 * 2);
    bf16_t* h_phi   = (bf16_t*)carve((size_t)Nn * 512 * 2);
    bf16_t* fcT  = (bf16_t*)carve((size_t)128 * 1024 * 2);
    bf16_t* w1T  = (bf16_t*)carve((size_t)3 * 256 * 128 * 2);
    bf16_t* w2T  = (bf16_t*)carve((size_t)3 * 128 * 256 * 2);
    bf16_t* phiT = (bf16_t*)carve((size_t)512 * 512 * 2);
    bf16_t* Bcat = (bf16_t*)carve((size_t)1024 * 512 * 2);
    float* bias_cat = (float*)carve(1024 * 4);
    int*   deg    = (int*)carve((size_t)Nn * 4);
    int*   loc    = (int*)carve((size_t)Nn * 4);
    int*   bsum   = (int*)carve(256 * 4);
    int*   boff   = (int*)carve(256 * 4);
    int*   offArr = (int*)carve((size_t)(Nn + 1) * 4);
    int*   cursor = (int*)carve((size_t)Nn * 4);
    int*   csr    = (int*)carve((size_t)E * 4);
    float* sN     = (float*)carve((size_t)Nn * 4);
    float* pmax   = (float*)carve(64 * 4);
    float* psum   = (float*)carve(64 * 4);
    float* red    = (float*)carve(64);
    float* hp     = (float*)carve(512 * 4);
    float* h2g    = (float*)carve(512 * 4);

    // fused weight prep + buffer zeroing (deg/sN/hp) in one launch
    const int ZB = (Nn + 255) / 256;
    k_prep<<<1090 + 2 * ZB + 1, 256, 0, stream>>>(fc_w, fcT, conv_w1, w1T, conv_w2, w2T, phi_w, phiT,
                                                  aw, bw, Bcat, ab, bb, bias_cat, deg, sN, hp, Nn);

    // CSR build (parallel scan)
    const int SB = (Nn + 1023) / 1024;
    k_deg<<<(E + 255) / 256, 256, 0, stream>>>(eidx + E, deg, E);
    k_scan_a<<<SB, 1024, 0, stream>>>(deg, loc, bsum, Nn);
    k_scan_b<<<1, 64, 0, stream>>>(bsum, SB, boff, offArr + Nn);
    k_scan_c<<<SB, 1024, 0, stream>>>(loc, boff, offArr, cursor, Nn);
    k_fill<<<(E + 255) / 256, 256, 0, stream>>>(eidx, eidx + E, cursor, csr, E);

    const int MT128 = (Nn + 127) / 128;
    const int MT512 = (Nn + 511) / 512;
    const int agB = (Nn + 3) / 4;

    // fc: x1 = relu(x @ fc_w + b) -> x_cat_b[:,0:128] + compact xl0
    k_gemm_fcP<<<MT128, 256, 0, stream>>>(x, 1024, fcT, fc_b, x_cat_b, 512, xl0, Nn, 1024);

    const bf16_t* xls[3] = {xl0, xl1, xl2};
    for (int i = 0; i < 3; i++) {
        k_agg<<<agB, 256, 0, stream>>>(xls[i], offArr, csr, haux, conv_t, i, Nn);
        if (i == 0)
            k_convf<0><<<MT128, 512, 0, stream>>>(haux, w1T, conv_b1, conv_lnw, conv_lnb,
                                                  w2T, conv_b2, nullptr, nullptr, nullptr,
                                                  x_cat_b + 128, xs1, xl1, Nn);
        else if (i == 1)
            k_convf<1><<<MT128, 512, 0, stream>>>(haux, w1T + (size_t)256 * 128, conv_b1 + 256,
                                                  conv_lnw + 256, conv_lnb + 256,
                                                  w2T + (size_t)128 * 256, conv_b2 + 128,
                                                  norm_w + 128, norm_b + 128, xs1,
                                                  x_cat_b + 256, xs2, xl2, Nn);
        else
            k_convf<1><<<MT128, 512, 0, stream>>>(haux, w1T + (size_t)2 * 256 * 128, conv_b1 + 512,
                                                  conv_lnw + 512, conv_lnb + 512,
                                                  w2T + (size_t)2 * 128 * 256, conv_b2 + 256,
                                                  norm_w + 256, norm_b + 256, xs2,
                                                  x_cat_b + 384, nullptr, nullptr, Nn);
    }

    // head: BM=512/BN=128 1-phase (2 blocks/CU x 16 waves = 100% wave occupancy)
    k_gemm1<512, 3><<<MT512 * 4, 1024, 0, stream>>>(x_cat_b, 512, phiT, phi_b, h_phi, 512,
                                                    Nn, 512, 4, nullptr, nullptr);
    k_gemm1<512, 5><<<MT512 * 8, 1024, 0, stream>>>(h_phi, 512, Bcat, bias_cat, nullptr, 0,
                                                    Nn, 512, 8, cwp, sN);
    k_sred_a<<<64, 256, 0, stream>>>(sN, Nn, pmax, psum);
    k_sred_b<<<1, 64, 0, stream>>>(pmax, psum, 64, red);
    k_pool<<<256, 256, 0, stream>>>(h_phi, sN, red, hp, Nn);
    k_tail_a<<<8, 256, 0, stream>>>(hp, rho_w, rho_b, h2g);
    k_tail_b<<<1, 256, 0, stream>>>(h2g, cls_w, cls_b, (float*)d_out);
}

// Round 13
// 560.719 us; speedup vs baseline: 1.0772x; 1.0772x over previous
//
#include <hip/hip_runtime.h>
#include <hip/hip_bf16.h>
#include <math.h>

typedef __bf16 bf16_t;
typedef __attribute__((ext_vector_type(8))) __bf16 bf16x8;
typedef __attribute__((ext_vector_type(2))) __bf16 bf16x2;
typedef __attribute__((ext_vector_type(4))) float f32x4;

// async global->LDS, 16B per lane. dst must be the wave-uniform base (HW adds lane*16).
__device__ __forceinline__ void gld_lds16(const void* g, void* s) {
    __builtin_amdgcn_global_load_lds(
        (__attribute__((address_space(1))) unsigned int*)g,
        (__attribute__((address_space(3))) unsigned int*)s,
        16, 0, 0);
}

// bijective XCD chunk swizzle (m204) + col-fast decode
__device__ __forceinline__ int2 sw_decode(int orig, int nwg, int NT) {
    int q = nwg >> 3, r = nwg & 7, xcd = orig & 7, idx = orig >> 3;
    int wg = (xcd < r ? xcd * (q + 1) : r * (q + 1) + (xcd - r) * q) + idx;
    int bx = wg / NT, by = wg - bx * NT;
    return make_int2(bx, by);
}

// ---------------------------------------------------------------- fused weight prep + buffer zeroing
__device__ __forceinline__ void tconv_tile(const float* __restrict__ in, bf16_t* __restrict__ out,
                                           int R, int C, int rs, int ro, int bx, int by)
{
    __shared__ float tile[32][33];
    int bc = bx * 32, br = by * 32;
    int tx = threadIdx.x & 31, ty = threadIdx.x >> 5;
    #pragma unroll
    for (int i = 0; i < 32; i += 8) {
        int r = br + ty + i, c = bc + tx;
        tile[ty + i][tx] = (r < R && c < C) ? in[(long)r * C + c] : 0.f;
    }
    __syncthreads();
    #pragma unroll
    for (int i = 0; i < 32; i += 8) {
        int c = bc + ty + i, r = br + tx;
        if (c < C && r < R) out[((long)c * rs + ro) * R + r] = (bf16_t)tile[tx][ty + i];
    }
}

__global__ __launch_bounds__(256) void k_prep(const float* __restrict__ fc_w, bf16_t* __restrict__ fcT,
                                              const float* __restrict__ conv_w1, bf16_t* __restrict__ w1T,
                                              const float* __restrict__ conv_w2, bf16_t* __restrict__ w2T,
                                              const float* __restrict__ phi_w, bf16_t* __restrict__ phiT,
                                              const float* __restrict__ aw, const float* __restrict__ bw,
                                              bf16_t* __restrict__ Bcat,
                                              const float* __restrict__ abias, const float* __restrict__ bbias,
                                              float* __restrict__ bias_cat,
                                              int* __restrict__ deg, float* __restrict__ sN,
                                              float* __restrict__ hp, int Nn)
{
    int b = blockIdx.x;
    if (b < 128) {
        tconv_tile(fc_w, fcT, 1024, 128, 1, 0, b & 3, b >> 2);
    } else if (b < 224) {
        int i = (b - 128) >> 5, bb = (b - 128) & 31;
        tconv_tile(conv_w1 + (size_t)i * 128 * 256, w1T + (size_t)i * 256 * 128, 128, 256, 1, 0, bb & 7, bb >> 3);
    } else if (b < 320) {
        int i = (b - 224) >> 5, bb = (b - 224) & 31;
        tconv_tile(conv_w2 + (size_t)i * 256 * 128, w2T + (size_t)i * 128 * 256, 256, 128, 1, 0, bb & 3, bb >> 2);
    } else if (b < 576) {
        int bb = b - 320;
        tconv_tile(phi_w, phiT, 512, 512, 1, 0, bb & 15, bb >> 4);
    } else if (b < 832) {
        int bb = b - 576;
        tconv_tile(aw, Bcat, 512, 512, 2, 0, bb & 15, bb >> 4);
    } else if (b < 1088) {
        int bb = b - 832;
        tconv_tile(bw, Bcat, 512, 512, 2, 1, bb & 15, bb >> 4);
    } else if (b < 1090) {
        int i = (b - 1088) * 256 + threadIdx.x;
        if (i < 512) { bias_cat[2 * i] = abias[i]; bias_cat[2 * i + 1] = bbias[i]; }
    } else if (b < 1286) {
        int i = (b - 1090) * 256 + threadIdx.x;
        if (i < Nn) deg[i] = 0;
    } else if (b < 1482) {
        int i = (b - 1286) * 256 + threadIdx.x;
        if (i < Nn) sN[i] = 0.f;
    } else {
        // zero BOTH halves of hp[512] (256-thread block)
        hp[threadIdx.x] = 0.f;
        hp[threadIdx.x + 256] = 0.f;
    }
}

// ---------------------------------------------------------------- CSR build
__global__ __launch_bounds__(256) void k_deg(const int* __restrict__ dst, int* __restrict__ deg, int E)
{
    int e = blockIdx.x * 256 + threadIdx.x;
    if (e < E) atomicAdd(&deg[dst[e]], 1);
}

__global__ __launch_bounds__(1024) void k_scan_a(const int* __restrict__ deg, int* __restrict__ loc,
                                                 int* __restrict__ bsum, int n)
{
    __shared__ int wsum[16];
    int t = threadIdx.x, lane = t & 63, wid = t >> 6;
    int idx = blockIdx.x * 1024 + t;
    int v = (idx < n) ? deg[idx] : 0;
    int x = v;
    #pragma unroll
    for (int d = 1; d < 64; d <<= 1) { int o = __shfl_up(x, d); if (lane >= d) x += o; }
    if (lane == 63) wsum[wid] = x;
    __syncthreads();
    if (wid == 0 && lane < 16) {
        int y = wsum[lane];
        #pragma unroll
        for (int d = 1; d < 16; d <<= 1) { int o = __shfl_up(y, d); if (lane >= d) y += o; }
        wsum[lane] = y;
    }
    __syncthreads();
    int wbase = (wid == 0) ? 0 : wsum[wid - 1];
    if (idx < n) loc[idx] = wbase + x - v;
    if (t == 1023) bsum[blockIdx.x] = wsum[15];
}

__global__ __launch_bounds__(64) void k_scan_b(const int* __restrict__ bsum, int nb,
                                               int* __restrict__ boff, int* __restrict__ off_n)
{
    int lane = threadIdx.x;
    int base = 0;
    for (int c = 0; c < nb; c += 64) {
        int i = c + lane;
        int v = (i < nb) ? bsum[i] : 0;
        int x = v;
        #pragma unroll
        for (int d = 1; d < 64; d <<= 1) { int o = __shfl_up(x, d); if (lane >= d) x += o; }
        if (i < nb) boff[i] = base + x - v;
        base += __shfl(x, 63);
    }
    if (lane == 0) *off_n = base;
}

__global__ __launch_bounds__(1024) void k_scan_c(const int* __restrict__ loc, const int* __restrict__ boff,
                                                 int* __restrict__ off, int* __restrict__ cursor, int n)
{
    int idx = blockIdx.x * 1024 + threadIdx.x;
    if (idx < n) { int v = loc[idx] + boff[blockIdx.x]; off[idx] = v; cursor[idx] = v; }
}

__global__ __launch_bounds__(256) void k_fill(const int* __restrict__ src, const int* __restrict__ dst,
                                              int* __restrict__ cursor, int* __restrict__ csr, int E)
{
    int e = blockIdx.x * 256 + threadIdx.x;
    if (e < E) {
        int d = dst[e];
        int pos = atomicAdd(&cursor[d], 1);
        csr[pos] = src[e];
    }
}

// ---------------------------------------------------------------- GENConv aggregation, 8-deep prefetch
__global__ __launch_bounds__(256) void k_agg(const bf16_t* __restrict__ X,
                                             const int* __restrict__ off, const int* __restrict__ csr,
                                             bf16_t* __restrict__ haux,
                                             const float* __restrict__ tptr, int ti, int Nn)
{
    int w = (blockIdx.x * 256 + threadIdx.x) >> 6;
    if (w >= Nn) return;
    int lane = threadIdx.x & 63;
    float t = tptr[ti];
    int e0 = off[w], e1 = off[w + 1];
    float m0 = -__builtin_inff(), m1 = -__builtin_inff();
    float s0 = 0.f, s1 = 0.f, g0 = 0.f, g1 = 0.f;

    auto proc = [&](bf16x2 xv) {
        float msg0 = fmaxf((float)xv[0], 0.f) + 1e-7f;
        float msg1 = fmaxf((float)xv[1], 0.f) + 1e-7f;
        float v0 = msg0 * t, v1 = msg1 * t;
        if (v0 > m0) { float sc = __expf(m0 - v0); s0 *= sc; g0 *= sc; m0 = v0; }
        float p0 = __expf(v0 - m0); s0 += p0; g0 += msg0 * p0;
        if (v1 > m1) { float sc = __expf(m1 - v1); s1 *= sc; g1 *= sc; m1 = v1; }
        float p1 = __expf(v1 - m1); s1 += p1; g1 += msg1 * p1;
    };

    int e = e0;
    for (; e + 8 <= e1; e += 8) {
        int i0 = csr[e],     i1 = csr[e + 1], i2 = csr[e + 2], i3 = csr[e + 3];
        int i4 = csr[e + 4], i5 = csr[e + 5], i6 = csr[e + 6], i7 = csr[e + 7];
        bf16x2 v0 = *(const bf16x2*)(X + (long)i0 * 128 + lane * 2);
        bf16x2 v1 = *(const bf16x2*)(X + (long)i1 * 128 + lane * 2);
        bf16x2 v2 = *(const bf16x2*)(X + (long)i2 * 128 + lane * 2);
        bf16x2 v3 = *(const bf16x2*)(X + (long)i3 * 128 + lane * 2);
        bf16x2 v4 = *(const bf16x2*)(X + (long)i4 * 128 + lane * 2);
        bf16x2 v5 = *(const bf16x2*)(X + (long)i5 * 128 + lane * 2);
        bf16x2 v6 = *(const bf16x2*)(X + (long)i6 * 128 + lane * 2);
        bf16x2 v7 = *(const bf16x2*)(X + (long)i7 * 128 + lane * 2);
        proc(v0); proc(v1); proc(v2); proc(v3); proc(v4); proc(v5); proc(v6); proc(v7);
    }
    for (; e + 4 <= e1; e += 4) {
        int i0 = csr[e], i1 = csr[e + 1], i2 = csr[e + 2], i3 = csr[e + 3];
        bf16x2 v0 = *(const bf16x2*)(X + (long)i0 * 128 + lane * 2);
        bf16x2 v1 = *(const bf16x2*)(X + (long)i1 * 128 + lane * 2);
        bf16x2 v2 = *(const bf16x2*)(X + (long)i2 * 128 + lane * 2);
        bf16x2 v3 = *(const bf16x2*)(X + (long)i3 * 128 + lane * 2);
        proc(v0); proc(v1); proc(v2); proc(v3);
    }
    for (; e < e1; e++) {
        int s = csr[e];
        bf16x2 xv = *(const bf16x2*)(X + (long)s * 128 + lane * 2);
        proc(xv);
    }
    float a0 = g0 / (s0 + 1e-16f);
    float a1 = g1 / (s1 + 1e-16f);
    bf16x2 xr = *(const bf16x2*)(X + (long)w * 128 + lane * 2);
    bf16_t* outp = haux + (long)w * 128 + lane * 2;
    outp[0] = (bf16_t)((float)xr[0] + a0);
    outp[1] = (bf16_t)((float)xr[1] + a1);
}

// ---------------------------------------------------------------- 1-phase GEMM, BM=256/BN=128 (PROVEN optimum):
// 512 thr, 8 waves (4Mx2N), 48 KB single-buffer -> 3 blocks/CU, 24 waves. occ-hint 4 waves/SIMD.
// EPI 3 = bf16 relu store; EPI 5 = interleaved attention epilogue (cols 2j/2j+1 = a/b).
template<int BM, int EPI>
__global__ __launch_bounds__(512, 4)
void k_gemm1(const bf16_t* __restrict__ A, int lda,
             const bf16_t* __restrict__ BT,
             const float* __restrict__ bias,
             bf16_t* __restrict__ Cout, int ldc,
             int M, int K, int NT,
             const float* __restrict__ cw,
             float* __restrict__ sout)
{
    constexpr int THREADS = 512;
    constexpr int ACH = BM * 8 / THREADS;      // 4 for BM=256
    constexpr int BCH = 128 * 8 / THREADS;     // 2
    __shared__ __align__(16) bf16_t lA[BM * 64];
    __shared__ __align__(16) bf16_t lB[128 * 64];
    int2 bxy = sw_decode(blockIdx.x, gridDim.x, NT);
    const int m0 = bxy.x * BM, n0 = bxy.y * 128;
    const int tid = threadIdx.x, lane = tid & 63, wid = tid >> 6;
    const int rbase = (wid >> 1) * 64, cbase = (wid & 1) * 64;
    const int lrow = lane & 15, kg = lane >> 4;
    const int uw = tid & ~63;

    f32x4 acc[4][4];
    #pragma unroll
    for (int m = 0; m < 4; m++)
        #pragma unroll
        for (int n = 0; n < 4; n++)
            #pragma unroll
            for (int r = 0; r < 4; r++) acc[m][n][r] = 0.f;

    auto stage = [&](int k0) {
        #pragma unroll
        for (int c = 0; c < ACH; c++) {
            int s = c * THREADS + tid, row = s >> 3, k8s = (s & 7) ^ (row & 7);
            int gr = m0 + row; gr = gr < M ? gr : M - 1;   // clamp: garbage only in rows >= M
            gld_lds16(A + (long)gr * lda + k0 + k8s * 8, lA + (c * THREADS + uw) * 8);
        }
        #pragma unroll
        for (int c = 0; c < BCH; c++) {
            int s = c * THREADS + tid, row = s >> 3, k8s = (s & 7) ^ (row & 7);
            gld_lds16(BT + (long)(n0 + row) * K + k0 + k8s * 8, lB + (c * THREADS + uw) * 8);
        }
    };
    auto compute = [&]() {
        #pragma unroll
        for (int ks = 0; ks < 2; ks++) {
            int k8 = ks * 4 + kg;
            bf16x8 af[4], bfr[4];
            #pragma unroll
            for (int m = 0; m < 4; m++) {
                int r = rbase + m * 16 + lrow;
                af[m] = *(const bf16x8*)&lA[(r * 8 + (k8 ^ (r & 7))) * 8];
            }
            #pragma unroll
            for (int n = 0; n < 4; n++) {
                int r = cbase + n * 16 + lrow;
                bfr[n] = *(const bf16x8*)&lB[(r * 8 + (k8 ^ (r & 7))) * 8];
            }
            #pragma unroll
            for (int m = 0; m < 4; m++)
                #pragma unroll
                for (int n = 0; n < 4; n++)
                    acc[m][n] = __builtin_amdgcn_mfma_f32_16x16x32_bf16(af[m], bfr[n], acc[m][n], 0, 0, 0);
        }
    };

    for (int k0 = 0; k0 < K; k0 += 64) {
        stage(k0);
        __syncthreads();
        compute();
        __syncthreads();
    }

    if constexpr (EPI == 5) {
        #pragma unroll
        for (int m = 0; m < 4; m++) {
            #pragma unroll
            for (int r = 0; r < 4; r++) {
                int row = m0 + rbase + m * 16 + kg * 4 + r;   // C/D: col=lane&15, row=(lane>>4)*4+reg
                float val = 0.f;
                #pragma unroll
                for (int n = 0; n < 4; n++) {
                    int col = n0 + cbase + n * 16 + lrow;
                    float xv = acc[m][n][r] + bias[col];
                    int odd = col & 1;
                    float z = odd ? xv : 2.f * xv;
                    float sg = 1.f / (1.f + __expf(-z));
                    float f = odd ? sg : (2.f * sg - 1.f);    // even col: tanh via sigmoid
                    float partner = __shfl_xor(f, 1);
                    float prod = f * partner;
                    val += odd ? 0.f : prod * cw[col >> 1];
                }
                #pragma unroll
                for (int o = 1; o < 16; o <<= 1) val += __shfl_xor(val, o);
                if (lrow == 0 && row < M) atomicAdd(&sout[row], val);
            }
        }
    } else {
        #pragma unroll
        for (int m = 0; m < 4; m++) {
            #pragma unroll
            for (int r = 0; r < 4; r++) {
                int row = m0 + rbase + m * 16 + kg * 4 + r;
                if (row >= M) continue;
                #pragma unroll
                for (int n = 0; n < 4; n++) {
                    int col = n0 + cbase + n * 16 + lrow;
                    float xv = fmaxf(acc[m][n][r] + bias[col], 0.f);
                    Cout[(long)row * ldc + col] = (bf16_t)xv;
                }
            }
        }
    }
}

// ---------------------------------------------------------------- fc GEMM: BM=128, BN=128, f32 A, 1-phase.
__global__ __launch_bounds__(256) void k_gemm_fcP(const float* __restrict__ Aptr, int lda,
                                                  const bf16_t* __restrict__ BT,
                                                  const float* __restrict__ bias,
                                                  bf16_t* __restrict__ Cout, int ldc,
                                                  bf16_t* __restrict__ Cout2,
                                                  int M, int K)
{
    __shared__ __align__(16) bf16_t lA[128 * 64];
    __shared__ __align__(16) bf16_t lB[128 * 64];
    const int m0 = blockIdx.x * 128;
    const int tid = threadIdx.x, lane = tid & 63, wid = tid >> 6;
    const int rbase = (wid >> 1) * 64, cbase = (wid & 1) * 64;
    const int lrow = lane & 15, kg = lane >> 4;
    const int uw = tid & ~63;

    f32x4 acc[4][4];
    #pragma unroll
    for (int m = 0; m < 4; m++)
        #pragma unroll
        for (int n = 0; n < 4; n++)
            #pragma unroll
            for (int r = 0; r < 4; r++) acc[m][n][r] = 0.f;

    f32x4 fa[8];

    for (int k0 = 0; k0 < K; k0 += 64) {
        #pragma unroll
        for (int c = 0; c < 4; c++) {
            int s = c * 256 + tid, row = s >> 3, k8 = s & 7;
            int gr = m0 + row; gr = gr < M ? gr : M - 1;
            const float* sp = Aptr + (long)gr * lda + k0 + k8 * 8;
            fa[2 * c] = *(const f32x4*)sp;
            fa[2 * c + 1] = *(const f32x4*)(sp + 4);
        }
        #pragma unroll
        for (int c = 0; c < 4; c++) {
            int s = c * 256 + tid, row = s >> 3, k8s = (s & 7) ^ (row & 7);
            gld_lds16(BT + (long)row * K + k0 + k8s * 8, lB + (c * 256 + uw) * 8);
        }
        #pragma unroll
        for (int c = 0; c < 4; c++) {
            int s = c * 256 + tid, row = s >> 3, k8 = s & 7;
            bf16x8 v;
            #pragma unroll
            for (int j = 0; j < 4; j++) { v[j] = (bf16_t)fa[2 * c][j]; v[4 + j] = (bf16_t)fa[2 * c + 1][j]; }
            *(bf16x8*)&lA[(row * 8 + (k8 ^ (row & 7))) * 8] = v;
        }
        __syncthreads();
        #pragma unroll
        for (int ks = 0; ks < 2; ks++) {
            int k8 = ks * 4 + kg;
            bf16x8 af[4], bfr[4];
            #pragma unroll
            for (int m = 0; m < 4; m++) {
                int r = rbase + m * 16 + lrow;
                af[m] = *(const bf16x8*)&lA[(r * 8 + (k8 ^ (r & 7))) * 8];
            }
            #pragma unroll
            for (int n = 0; n < 4; n++) {
                int r = cbase + n * 16 + lrow;
                bfr[n] = *(const bf16x8*)&lB[(r * 8 + (k8 ^ (r & 7))) * 8];
            }
            #pragma unroll
            for (int m = 0; m < 4; m++)
                #pragma unroll
                for (int n = 0; n < 4; n++)
                    acc[m][n] = __builtin_amdgcn_mfma_f32_16x16x32_bf16(af[m], bfr[n], acc[m][n], 0, 0, 0);
        }
        __syncthreads();
    }

    #pragma unroll
    for (int m = 0; m < 4; m++) {
        #pragma unroll
        for (int r = 0; r < 4; r++) {
            int row = m0 + rbase + m * 16 + kg * 4 + r;
            if (row >= M) continue;
            #pragma unroll
            for (int n = 0; n < 4; n++) {
                int col = cbase + n * 16 + lrow;
                float xv = fmaxf(acc[m][n][r] + bias[col], 0.f);
                Cout[(long)row * ldc + col] = (bf16_t)xv;
                Cout2[(long)row * 128 + col] = (bf16_t)xv;
            }
        }
    }
}

// ---------------------------------------------------------------- FUSED conv MLP v2 (proven)
template<int MODE>  // 0: y=conv; 1: y = xs_in + relu(LN128(conv))
__global__ __launch_bounds__(512) void k_convf(const bf16_t* __restrict__ A,
                                               const bf16_t* __restrict__ B1T,   // [256][128]
                                               const float* __restrict__ b1,
                                               const float* __restrict__ lnw, const float* __restrict__ lnb,
                                               const bf16_t* __restrict__ B2T,   // [128][256]
                                               const float* __restrict__ b2,
                                               const float* __restrict__ nw, const float* __restrict__ nb,
                                               const float* __restrict__ xs_in,
                                               bf16_t* __restrict__ xcat_out,
                                               float* __restrict__ xs_out, bf16_t* __restrict__ xl_out,
                                               int M)
{
    __shared__ __align__(16) bf16_t lA[128 * 128];
    __shared__ __align__(16) bf16_t lB1[256 * 128];
    __shared__ __align__(16) bf16_t lB2a[128 * 128];
    bf16_t* h1 = lB1;
    bf16_t* lB2b = lA;

    const int m0 = blockIdx.x * 128;
    const int tid = threadIdx.x, lane = tid & 63, w = tid >> 6;
    const int lrow = lane & 15, kg = lane >> 4;
    const int uw = tid & ~63;

    #pragma unroll
    for (int c = 0; c < 4; c++) {
        int s = c * 512 + tid, row = s >> 4, sl = s & 15;
        int k8 = (sl & 8) | ((sl & 7) ^ (row & 7));
        int gr = m0 + row; gr = gr < M ? gr : M - 1;
        gld_lds16(A + (long)gr * 128 + k8 * 8, lA + (c * 512 + uw) * 8);
    }
    #pragma unroll
    for (int c = 0; c < 8; c++) {
        int s = c * 512 + tid, row = s >> 4, sl = s & 15;
        int k8 = (sl & 8) | ((sl & 7) ^ (row & 7));
        gld_lds16(B1T + (long)row * 128 + k8 * 8, lB1 + (c * 512 + uw) * 8);
    }
    #pragma unroll
    for (int c = 0; c < 4; c++) {
        int s = c * 512 + tid, row = s >> 4, sl = s & 15;
        int k8 = (sl & 8) | ((sl & 7) ^ (row & 7));
        gld_lds16(B2T + (long)row * 256 + k8 * 8, lB2a + (c * 512 + uw) * 8);
    }
    asm volatile("s_waitcnt vmcnt(4)" ::: "memory");
    __builtin_amdgcn_s_barrier();

    f32x4 acc1[16];
    #pragma unroll
    for (int n = 0; n < 16; n++)
        #pragma unroll
        for (int r = 0; r < 4; r++) acc1[n][r] = 0.f;
    #pragma unroll
    for (int ks = 0; ks < 4; ks++) {
        int k8 = ks * 4 + kg;
        int ra = w * 16 + lrow;
        bf16x8 af = *(const bf16x8*)&lA[(ra * 16 + ((k8 & 8) | ((k8 & 7) ^ (ra & 7)))) * 8];
        #pragma unroll
        for (int n = 0; n < 16; n++) {
            int rb = n * 16 + lrow;
            bf16x8 bf = *(const bf16x8*)&lB1[(rb * 16 + ((k8 & 8) | ((k8 & 7) ^ (rb & 7)))) * 8];
            acc1[n] = __builtin_amdgcn_mfma_f32_16x16x32_bf16(af, bf, acc1[n], 0, 0, 0);
        }
    }

    float hv[4][16];
    #pragma unroll
    for (int r = 0; r < 4; r++) {
        float s1 = 0.f, s2 = 0.f;
        #pragma unroll
        for (int n = 0; n < 16; n++) {
            int col = n * 16 + lrow;
            float xv = acc1[n][r] + b1[col];
            hv[r][n] = xv;
            s1 += xv; s2 += xv * xv;
        }
        #pragma unroll
        for (int o = 1; o < 16; o <<= 1) { s1 += __shfl_xor(s1, o); s2 += __shfl_xor(s2, o); }
        float mu = s1 * (1.f / 256.f);
        float var = s2 * (1.f / 256.f) - mu * mu;
        float rstd = rsqrtf(var + 1e-5f);
        #pragma unroll
        for (int n = 0; n < 16; n++) {
            int col = n * 16 + lrow;
            hv[r][n] = fmaxf((hv[r][n] - mu) * rstd * lnw[col] + lnb[col], 0.f);
        }
    }

    __builtin_amdgcn_s_barrier();

    #pragma unroll
    for (int r = 0; r < 4; r++) {
        int row = w * 16 + kg * 4 + r;
        #pragma unroll
        for (int n = 0; n < 16; n++) {
            int col = n * 16 + lrow;
            int chunk = col >> 3;
            int cs = (chunk & 24) | ((chunk & 7) ^ (row & 7));
            h1[row * 256 + cs * 8 + (col & 7)] = (bf16_t)hv[r][n];
        }
    }
    #pragma unroll
    for (int c = 0; c < 4; c++) {
        int s = c * 512 + tid, row = s >> 4, sl = s & 15;
        int k8l = (sl & 8) | ((sl & 7) ^ (row & 7));
        gld_lds16(B2T + (long)row * 256 + (16 + k8l) * 8, lB2b + (c * 512 + uw) * 8);
    }

    f32x4 acc2[8];
    #pragma unroll
    for (int n = 0; n < 8; n++)
        #pragma unroll
        for (int r = 0; r < 4; r++) acc2[n][r] = 0.f;
    #pragma unroll
    for (int ks = 0; ks < 4; ks++) {
        int k8 = ks * 4 + kg;
        int ra = w * 16 + lrow;
        bf16x8 af = *(const bf16x8*)&h1[(ra * 32 + ((k8 & 24) | ((k8 & 7) ^ (ra & 7)))) * 8];
        #pragma unroll
        for (int n = 0; n < 8; n++) {
            int rb = n * 16 + lrow;
            bf16x8 bf = *(const bf16x8*)&lB2a[(rb * 16 + ((k8 & 8) | ((k8 & 7) ^ (rb & 7)))) * 8];
            acc2[n] = __builtin_amdgcn_mfma_f32_16x16x32_bf16(af, bf, acc2[n], 0, 0, 0);
        }
    }
    asm volatile("s_waitcnt vmcnt(0)" ::: "memory");
    __builtin_amdgcn_s_barrier();

    #pragma unroll
    for (int ks = 0; ks < 4; ks++) {
        int k8 = 16 + ks * 4 + kg;
        int k8l = k8 - 16;
        int ra = w * 16 + lrow;
        bf16x8 af = *(const bf16x8*)&h1[(ra * 32 + ((k8 & 24) | ((k8 & 7) ^ (ra & 7)))) * 8];
        #pragma unroll
        for (int n = 0; n < 8; n++) {
            int rb = n * 16 + lrow;
            bf16x8 bf = *(const bf16x8*)&lB2b[(rb * 16 + ((k8l & 8) | ((k8l & 7) ^ (rb & 7)))) * 8];
            acc2[n] = __builtin_amdgcn_mfma_f32_16x16x32_bf16(af, bf, acc2[n], 0, 0, 0);
        }
    }

    #pragma unroll
    for (int r = 0; r < 4; r++) {
        int row = m0 + w * 16 + kg * 4 + r;
        float xv[8];
        #pragma unroll
        for (int n = 0; n < 8; n++) xv[n] = acc2[n][r] + b2[n * 16 + lrow];
        if constexpr (MODE == 1) {
            float s1 = 0.f, s2 = 0.f;
            #pragma unroll
            for (int n = 0; n < 8; n++) { s1 += xv[n]; s2 += xv[n] * xv[n]; }
            #pragma unroll
            for (int o = 1; o < 16; o <<= 1) { s1 += __shfl_xor(s1, o); s2 += __shfl_xor(s2, o); }
            float mu = s1 * (1.f / 128.f);
            float var = s2 * (1.f / 128.f) - mu * mu;
            float rstd = rsqrtf(var + 1e-5f);
            if (row < M) {
                #pragma unroll
                for (int n = 0; n < 8; n++) {
                    int col = n * 16 + lrow;
                    xv[n] = xs_in[(long)row * 128 + col] + fmaxf((xv[n] - mu) * rstd * nw[col] + nb[col], 0.f);
                }
            }
        }
        if (row < M) {
            #pragma unroll
            for (int n = 0; n < 8; n++) {
                int col = n * 16 + lrow;
                xcat_out[(long)row * 512 + col] = (bf16_t)xv[n];
                if (xs_out) xs_out[(long)row * 128 + col] = xv[n];
                if (xl_out) xl_out[(long)row * 128 + col] = (bf16_t)xv[n];
            }
        }
    }
}

// ---------------------------------------------------------------- parallel softmax stats: partials then combine
__global__ __launch_bounds__(256) void k_sred_a(const float* __restrict__ sN, int Nn,
                                                float* __restrict__ pmax, float* __restrict__ psum)
{
    __shared__ float red[4];
    int t = threadIdx.x, lane = t & 63, wid = t >> 6;
    int stride = gridDim.x * 256;
    float m = -__builtin_inff();
    for (int i = blockIdx.x * 256 + t; i < Nn; i += stride) m = fmaxf(m, sN[i]);
    #pragma unroll
    for (int o = 32; o >= 1; o >>= 1) m = fmaxf(m, __shfl_xor(m, o));
    if (lane == 0) red[wid] = m;
    __syncthreads();
    float bm = fmaxf(fmaxf(red[0], red[1]), fmaxf(red[2], red[3]));
    float s = 0.f;
    for (int i = blockIdx.x * 256 + t; i < Nn; i += stride) s += __expf(sN[i] - bm);
    #pragma unroll
    for (int o = 32; o >= 1; o >>= 1) s += __shfl_xor(s, o);
    __syncthreads();
    if (lane == 0) red[wid] = s;
    __syncthreads();
    if (t == 0) {
        pmax[blockIdx.x] = bm;
        psum[blockIdx.x] = red[0] + red[1] + red[2] + red[3];
    }
}

__global__ __launch_bounds__(64) void k_sred_b(const float* __restrict__ pmax, const float* __restrict__ psum,
                                               int nb, float* __restrict__ red)
{
    int lane = threadIdx.x;
    float m = (lane < nb) ? pmax[lane] : -__builtin_inff();
    #pragma unroll
    for (int o = 32; o >= 1; o >>= 1) m = fmaxf(m, __shfl_xor(m, o));
    float s = (lane < nb) ? psum[lane] * __expf(pmax[lane] - m) : 0.f;
    #pragma unroll
    for (int o = 32; o >= 1; o >>= 1) s += __shfl_xor(s, o);
    if (lane == 0) { red[0] = m; red[1] = s; }
}

// ---------------------------------------------------------------- hp[512] = sum_n softmax(s)[n] * h[n,:]
__global__ __launch_bounds__(256) void k_pool(const bf16_t* __restrict__ h, const float* __restrict__ sN,
                                              const float* __restrict__ red, float* __restrict__ hp, int Nn)
{
    __shared__ float part[4][512];
    int t = threadIdx.x, lane = t & 63, w = t >> 6;
    float m = red[0], inv = 1.f / red[1];
    float acc[8];
    #pragma unroll
    for (int j = 0; j < 8; j++) acc[j] = 0.f;
    for (int n = blockIdx.x * 4 + w; n < Nn; n += gridDim.x * 4) {
        float wgt = __expf(sN[n] - m) * inv;
        bf16x8 v = *(const bf16x8*)(h + (long)n * 512 + lane * 8);
        #pragma unroll
        for (int j = 0; j < 8; j++) acc[j] += wgt * (float)v[j];
    }
    #pragma unroll
    for (int j = 0; j < 8; j++) part[w][lane * 8 + j] = acc[j];
    __syncthreads();
    #pragma unroll
    for (int c = 0; c < 2; c++) {
        int col = c * 256 + t;
        float s = part[0][col] + part[1][col] + part[2][col] + part[3][col];
        atomicAdd(&hp[col], s);
    }
}

// ---------------------------------------------------------------- tail split: h2 = relu(hp@rho+rb) (8 blocks)
__global__ __launch_bounds__(256) void k_tail_a(const float* __restrict__ hp,
                                                const float* __restrict__ rho_w, const float* __restrict__ rho_b,
                                                float* __restrict__ h2g)
{
    __shared__ float hs[512];
    __shared__ float part[256];
    int t = threadIdx.x;
    hs[t] = hp[t]; hs[t + 256] = hp[t + 256];
    __syncthreads();
    int col = blockIdx.x * 64 + (t & 63);
    int ks = t >> 6;
    float acc = 0.f;
    for (int k = ks * 128; k < ks * 128 + 128; k++) acc += hs[k] * rho_w[(long)k * 512 + col];
    part[t] = acc;
    __syncthreads();
    if (ks == 0) {
        float v = part[t] + part[t + 64] + part[t + 128] + part[t + 192] + rho_b[col];
        h2g[col] = fmaxf(v, 0.f);
    }
}

__global__ __launch_bounds__(256) void k_tail_b(const float* __restrict__ h2g,
                                                const float* __restrict__ cls_w, const float* __restrict__ cls_b,
                                                float* __restrict__ out)
{
    __shared__ float wred[4][4];
    int t = threadIdx.x, lane = t & 63, wid = t >> 6;
    float a0 = 0.f, a1 = 0.f, a2 = 0.f, a3 = 0.f;
    for (int d = t; d < 512; d += 256) {
        float h = h2g[d];
        a0 += h * cls_w[d * 4 + 0];
        a1 += h * cls_w[d * 4 + 1];
        a2 += h * cls_w[d * 4 + 2];
        a3 += h * cls_w[d * 4 + 3];
    }
    #pragma unroll
    for (int o = 32; o >= 1; o >>= 1) {
        a0 += __shfl_xor(a0, o); a1 += __shfl_xor(a1, o);
        a2 += __shfl_xor(a2, o); a3 += __shfl_xor(a3, o);
    }
    if (lane == 0) { wred[wid][0] = a0; wred[wid][1] = a1; wred[wid][2] = a2; wred[wid][3] = a3; }
    __syncthreads();
    if (t < 4)
        out[t] = cls_b[t] + wred[0][t] + wred[1][t] + wred[2][t] + wred[3][t];
}

// ================================================================ host
extern "C" void kernel_launch(void* const* d_in, const int* in_sizes, int n_in,
                              void* d_out, int out_size, void* d_ws, size_t ws_size,
                              hipStream_t stream)
{
    const float* x       = (const float*)d_in[0];
    const int*   eidx    = (const int*)  d_in[1];
    const float* fc_w    = (const float*)d_in[2];
    const float* fc_b    = (const float*)d_in[3];
    const float* conv_w1 = (const float*)d_in[4];
    const float* conv_b1 = (const float*)d_in[5];
    const float* conv_lnw= (const float*)d_in[6];
    const float* conv_lnb= (const float*)d_in[7];
    const float* conv_w2 = (const float*)d_in[8];
    const float* conv_b2 = (const float*)d_in[9];
    const float* conv_t  = (const float*)d_in[10];
    const float* norm_w  = (const float*)d_in[11];
    const float* norm_b  = (const float*)d_in[12];
    const float* phi_w   = (const float*)d_in[13];
    const float* phi_b   = (const float*)d_in[14];
    const float* aw      = (const float*)d_in[15];
    const float* ab      = (const float*)d_in[16];
    const float* bw      = (const float*)d_in[17];
    const float* bb      = (const float*)d_in[18];
    const float* cwp     = (const float*)d_in[19];
    // d_in[20] = attn_c_b: constant pre-softmax shift, cancels
    const float* rho_w   = (const float*)d_in[21];
    const float* rho_b   = (const float*)d_in[22];
    const float* cls_w   = (const float*)d_in[23];
    const float* cls_b   = (const float*)d_in[24];

    const int Nn = in_sizes[0] / 1024;
    const int E  = in_sizes[1] / 2;

    char* p = (char*)d_ws;
    auto carve = [&](size_t bytes) { char* r = p; p += (bytes + 255) & ~(size_t)255; return r; };

    bf16_t* x_cat_b = (bf16_t*)carve((size_t)Nn * 512 * 2);
    bf16_t* haux    = (bf16_t*)carve((size_t)Nn * 128 * 2);
    float*  xs1     = (float*)carve((size_t)Nn * 128 * 4);
    float*  xs2     = (float*)carve((size_t)Nn * 128 * 4);
    bf16_t* xl0     = (bf16_t*)carve((size_t)Nn * 128 * 2);
    bf16_t* xl1     = (bf16_t*)carve((size_t)Nn * 128 * 2);
    bf16_t* xl2     = (bf16_t*)carve((size_t)Nn * 128 * 2);
    bf16_t* h_phi   = (bf16_t*)carve((size_t)Nn * 512 * 2);
    bf16_t* fcT  = (bf16_t*)carve((size_t)128 * 1024 * 2);
    bf16_t* w1T  = (bf16_t*)carve((size_t)3 * 256 * 128 * 2);
    bf16_t* w2T  = (bf16_t*)carve((size_t)3 * 128 * 256 * 2);
    bf16_t* phiT = (bf16_t*)carve((size_t)512 * 512 * 2);
    bf16_t* Bcat = (bf16_t*)carve((size_t)1024 * 512 * 2);
    float* bias_cat = (float*)carve(1024 * 4);
    int*   deg    = (int*)carve((size_t)Nn * 4);
    int*   loc    = (int*)carve((size_t)Nn * 4);
    int*   bsum   = (int*)carve(256 * 4);
    int*   boff   = (int*)carve(256 * 4);
    int*   offArr = (int*)carve((size_t)(Nn + 1) * 4);
    int*   cursor = (int*)carve((size_t)Nn * 4);
    int*   csr    = (int*)carve((size_t)E * 4);
    float* sN     = (float*)carve((size_t)Nn * 4);
    float* pmax   = (float*)carve(64 * 4);
    float* psum   = (float*)carve(64 * 4);
    float* red    = (float*)carve(64);
    float* hp     = (float*)carve(512 * 4);
    float* h2g    = (float*)carve(512 * 4);

    // fused weight prep + buffer zeroing (deg/sN/hp) in one launch
    const int ZB = (Nn + 255) / 256;
    k_prep<<<1090 + 2 * ZB + 1, 256, 0, stream>>>(fc_w, fcT, conv_w1, w1T, conv_w2, w2T, phi_w, phiT,
                                                  aw, bw, Bcat, ab, bb, bias_cat, deg, sN, hp, Nn);

    // CSR build (parallel scan)
    const int SB = (Nn + 1023) / 1024;
    k_deg<<<(E + 255) / 256, 256, 0, stream>>>(eidx + E, deg, E);
    k_scan_a<<<SB, 1024, 0, stream>>>(deg, loc, bsum, Nn);
    k_scan_b<<<1, 64, 0, stream>>>(bsum, SB, boff, offArr + Nn);
    k_scan_c<<<SB, 1024, 0, stream>>>(loc, boff, offArr, cursor, Nn);
    k_fill<<<(E + 255) / 256, 256, 0, stream>>>(eidx, eidx + E, cursor, csr, E);

    const int MT128 = (Nn + 127) / 128;
    const int MT256 = (Nn + 255) / 256;
    const int agB = (Nn + 3) / 4;

    // fc: x1 = relu(x @ fc_w + b) -> x_cat_b[:,0:128] + compact xl0
    k_gemm_fcP<<<MT128, 256, 0, stream>>>(x, 1024, fcT, fc_b, x_cat_b, 512, xl0, Nn, 1024);

    const bf16_t* xls[3] = {xl0, xl1, xl2};
    for (int i = 0; i < 3; i++) {
        k_agg<<<agB, 256, 0, stream>>>(xls[i], offArr, csr, haux, conv_t, i, Nn);
        if (i == 0)
            k_convf<0><<<MT128, 512, 0, stream>>>(haux, w1T, conv_b1, conv_lnw, conv_lnb,
                                                  w2T, conv_b2, nullptr, nullptr, nullptr,
                                                  x_cat_b + 128, xs1, xl1, Nn);
        else if (i == 1)
            k_convf<1><<<MT128, 512, 0, stream>>>(haux, w1T + (size_t)256 * 128, conv_b1 + 256,
                                                  conv_lnw + 256, conv_lnb + 256,
                                                  w2T + (size_t)128 * 256, conv_b2 + 128,
                                                  norm_w + 128, norm_b + 128, xs1,
                                                  x_cat_b + 256, xs2, xl2, Nn);
        else
            k_convf<1><<<MT128, 512, 0, stream>>>(haux, w1T + (size_t)2 * 256 * 128, conv_b1 + 512,
                                                  conv_lnw + 512, conv_lnb + 512,
                                                  w2T + (size_t)2 * 128 * 256, conv_b2 + 256,
                                                  norm_w + 256, norm_b + 256, xs2,
                                                  x_cat_b + 384, nullptr, nullptr, Nn);
    }

    // head: both at the PROVEN BM=256/BN=128 1-phase config (R7/R10 winner: 131 us attn)
    k_gemm1<256, 3><<<MT256 * 4, 512, 0, stream>>>(x_cat_b, 512, phiT, phi_b, h_phi, 512,
                                                   Nn, 512, 4, nullptr, nullptr);
    k_gemm1<256, 5><<<MT256 * 8, 512, 0, stream>>>(h_phi, 512, Bcat, bias_cat, nullptr, 0,
                                                   Nn, 512, 8, cwp, sN);
    k_sred_a<<<64, 256, 0, stream>>>(sN, Nn, pmax, psum);
    k_sred_b<<<1, 64, 0, stream>>>(pmax, psum, 64, red);
    k_pool<<<256, 256, 0, stream>>>(h_phi, sN, red, hp, Nn);
    k_tail_a<<<8, 256, 0, stream>>>(hp, rho_w, rho_b, h2g);
    k_tail_b<<<1, 256, 0, stream>>>(h2g, cls_w, cls_b, (float*)d_out);
}